// Round 4
// baseline (206.537 us; speedup 1.0000x reference)
//
#include <hip/hip_runtime.h>

typedef __bf16 bf16;
typedef __bf16 bf16x8 __attribute__((ext_vector_type(8)));
typedef float f32x4 __attribute__((ext_vector_type(4)));
typedef unsigned u32x4 __attribute__((ext_vector_type(4)));

#define MFMA16(a, b, c) __builtin_amdgcn_mfma_f32_16x16x32_bf16((a), (b), (c), 0, 0, 0)

static __device__ __forceinline__ bf16x8 ldg8(const bf16* p) {
  return *(const bf16x8*)p;
}
static __device__ __forceinline__ unsigned cvt_pk_bf16(float lo, float hi) {
  unsigned d;
  asm("v_cvt_pk_bf16_f32 %0, %1, %2" : "=v"(d) : "v"(lo), "v"(hi));
  return d;
}
static __device__ __forceinline__ void pl32_swap(unsigned& a, unsigned& b) {
  asm("v_permlane32_swap_b32 %0, %1" : "+v"(a), "+v"(b));
}
static __device__ __forceinline__ void pl16_swap(unsigned& a, unsigned& b) {
  asm("v_permlane16_swap_b32 %0, %1" : "+v"(a), "+v"(b));
}

// ===========================================================================
// Ladder: 803 -> ... -> 221 -> 222 (in-reg P) -> 204 (exp2+ones-MFMA+
// bitcast+split4) -> r3 FAILED (NaN: gemm128_core staged only HALF of each
// 128x32 tile -- 256 thr x 8 elem = 2048 of 4096; upper kchunks were
// uninitialized LDS). r4 = r3 with full staging (2x16B per thread per
// matrix) and GEMM launch_bounds (256,3) to avoid VGPR spill (64 acc regs).
// Design: 128^2-tile GEMM (BK=32, 16 MFMA : 8 ds_read/kstep, one-barrier
// reg-staged dbuf, [kchunk*128+row] packing = conflict-free both ways);
// flash: KV-split 2, merged QK/SM/PV clusters, in-reg P, ones-MFMA rowsum.
// ===========================================================================

// ---- pack x (fp32 [8192][512]) into P32 tiles: tile(mt,kc) = 128x32,
// linear = kchunk*1024 + r*8 + (kk&7), tiles at (mt*16+kc)*4096 ----
__global__ __launch_bounds__(256) void cvt_pack_x(const float* __restrict__ x,
                                                  bf16* __restrict__ Xp) {
  int mt = blockIdx.x, kc = blockIdx.y;
  int r = threadIdx.x >> 1;
  int khalf = threadIdx.x & 1;
  const float* src = x + (size_t)(mt * 128 + r) * 512 + kc * 32 + khalf * 16;
  float4 v0 = *(const float4*)(src + 0);
  float4 v1 = *(const float4*)(src + 4);
  float4 v2 = *(const float4*)(src + 8);
  float4 v3 = *(const float4*)(src + 12);
  bf16* tile = Xp + ((size_t)mt * 16 + kc) * 4096;
  bf16x8 a, b;
  a[0] = (bf16)v0.x; a[1] = (bf16)v0.y; a[2] = (bf16)v0.z; a[3] = (bf16)v0.w;
  a[4] = (bf16)v1.x; a[5] = (bf16)v1.y; a[6] = (bf16)v1.z; a[7] = (bf16)v1.w;
  b[0] = (bf16)v2.x; b[1] = (bf16)v2.y; b[2] = (bf16)v2.z; b[3] = (bf16)v2.w;
  b[4] = (bf16)v3.x; b[5] = (bf16)v3.y; b[6] = (bf16)v3.z; b[7] = (bf16)v3.w;
  int kc0 = khalf * 2;
  *(bf16x8*)&tile[(kc0 + 0) * 1024 + r * 8] = a;
  *(bf16x8*)&tile[(kc0 + 1) * 1024 + r * 8] = b;
}

// ---- pack W (fp32 [K][N]) transposed into P32T tiles: tile(nt,kc) holds
// (n,kk) at kchunk*1024 + n*8 + (kk&7); grid (16 kc, N/128 nt) ----
__global__ __launch_bounds__(256) void transpose_pack_w(const float* __restrict__ W,
                                                        bf16* __restrict__ Wp,
                                                        int N) {
  __shared__ float tile[32 * 129];
  int kc = blockIdx.x, nt = blockIdx.y;
  int row = threadIdx.x >> 3;            // 0..31 (k within chunk-of-32)
  int c0 = (threadIdx.x & 7) * 16;       // 16 fp32 per thread
  const float* src = W + (size_t)(kc * 32 + row) * N + nt * 128 + c0;
#pragma unroll
  for (int i = 0; i < 4; i++) {
    float4 v = *(const float4*)(src + i * 4);
    tile[row * 129 + c0 + i * 4 + 0] = v.x;
    tile[row * 129 + c0 + i * 4 + 1] = v.y;
    tile[row * 129 + c0 + i * 4 + 2] = v.z;
    tile[row * 129 + c0 + i * 4 + 3] = v.w;
  }
  __syncthreads();
  bf16* dst = Wp + ((size_t)nt * 16 + kc) * 4096;
#pragma unroll
  for (int half = 0; half < 2; half++) {
    int U = threadIdx.x + half * 256;    // unit = kchunk*128 + n
    int kchunk = U >> 7, n = U & 127;
    bf16x8 o;
#pragma unroll
    for (int j = 0; j < 8; j++) o[j] = (bf16)tile[(kchunk * 8 + j) * 129 + n];
    *(bf16x8*)&dst[U * 8] = o;
  }
}

// ---------------------------------------------------------------------------
// 128x128-tile GEMM core, BK=32, KC=16, 4 waves (2x2 quadrants of 64x64).
// One barrier per k-step, reg-staged double-buffer (race-free: readers of
// buf[cur] completed before barrier(kc-1); lgkmcnt(0) in syncthreads).
// FULL tile staged: 2 x (256 thr x 16B) per matrix = 4096 elements.
// LDS unit layout: unit = kchunk*128 + row -> staging ds_write consecutive
// 16B, frag ds_read consecutive 16B: conflict-free both ways.
// ---------------------------------------------------------------------------
__device__ __forceinline__ void gemm128_core(const bf16* __restrict__ At,
                                             const bf16* __restrict__ Bt,
                                             bf16* Ab0, bf16* Ab1, bf16* Bb0,
                                             bf16* Bb1, int tid, int wr, int wc,
                                             int l16, int quad, f32x4 acc[4][4]) {
  bf16x8 pa0 = ldg8(At + tid * 8);
  bf16x8 pa1 = ldg8(At + 2048 + tid * 8);
  bf16x8 pb0 = ldg8(Bt + tid * 8);
  bf16x8 pb1 = ldg8(Bt + 2048 + tid * 8);
#pragma unroll 2
  for (int kc = 0; kc < 16; kc++) {
    bf16* Ab = (kc & 1) ? Ab1 : Ab0;
    bf16* Bb = (kc & 1) ? Bb1 : Bb0;
    *(bf16x8*)&Ab[tid * 8] = pa0;
    *(bf16x8*)&Ab[2048 + tid * 8] = pa1;
    *(bf16x8*)&Bb[tid * 8] = pb0;
    *(bf16x8*)&Bb[2048 + tid * 8] = pb1;
    __syncthreads();
    if (kc < 15) {
      const bf16* an = At + (kc + 1) * 4096;
      const bf16* bn = Bt + (kc + 1) * 4096;
      pa0 = ldg8(an + tid * 8);
      pa1 = ldg8(an + 2048 + tid * 8);
      pb0 = ldg8(bn + tid * 8);
      pb1 = ldg8(bn + 2048 + tid * 8);
    }
    bf16x8 af[4], bf[4];
#pragma unroll
    for (int fi = 0; fi < 4; fi++)
      af[fi] = *(const bf16x8*)&Ab[(quad * 128 + wr * 64 + fi * 16 + l16) * 8];
#pragma unroll
    for (int fj = 0; fj < 4; fj++)
      bf[fj] = *(const bf16x8*)&Bb[(quad * 128 + wc * 64 + fj * 16 + l16) * 8];
    __builtin_amdgcn_s_setprio(1);
#pragma unroll
    for (int fi = 0; fi < 4; fi++)
#pragma unroll
      for (int fj = 0; fj < 4; fj++)
        acc[fi][fj] = MFMA16(af[fi], bf[fj], acc[fi][fj]);
    __builtin_amdgcn_s_setprio(0);
  }
}

// ---------------------------------------------------------------------------
// QKV projection, 128x128 tiles. Grid (64 mt, 12 nt). Q pre-scaled by
// 0.125*log2e. Q,K:[bh][n][d]; V tiled [bh][n>>6][d][n&63].
// ---------------------------------------------------------------------------
__global__ __launch_bounds__(256, 3) void qkv_gemm(const bf16* __restrict__ Xp,
                                                   const bf16* __restrict__ Wp1,
                                                   const float* __restrict__ bqkv,
                                                   bf16* __restrict__ Q,
                                                   bf16* __restrict__ Kh,
                                                   bf16* __restrict__ Vt) {
  int mt = blockIdx.x, nt = blockIdx.y;
  int tid = threadIdx.x;
  int wave = tid >> 6, lane = tid & 63;
  int l16 = lane & 15, quad = lane >> 4;
  int wr = wave >> 1, wc = wave & 1;

  __shared__ __align__(16) bf16 Ab[2][4096];
  __shared__ __align__(16) bf16 Bb[2][4096];

  f32x4 acc[4][4] = {};
  gemm128_core(Xp + (size_t)mt * 16 * 4096, Wp1 + (size_t)nt * 16 * 4096,
               Ab[0], Ab[1], Bb[0], Bb[1], tid, wr, wc, l16, quad, acc);

#pragma unroll
  for (int fj = 0; fj < 4; fj++) {
    int c = nt * 128 + wc * 64 + fj * 16 + l16;
    float bias = bqkv[c];
    int which = c >> 9, inner = c & 511;
    int h = inner >> 6, d = inner & 63;
#pragma unroll
    for (int fi = 0; fi < 4; fi++) {
#pragma unroll
      for (int r = 0; r < 4; r++) {
        int m = mt * 128 + wr * 64 + fi * 16 + quad * 4 + r;
        int b = m >> 12, n = m & 4095;
        int bh = b * 8 + h;
        float v = acc[fi][fj][r] + bias;
        if (which == 0)
          Q[((size_t)bh * 4096 + n) * 64 + d] = (bf16)(v * 0.18033688f);
        else if (which == 1)
          Kh[((size_t)bh * 4096 + n) * 64 + d] = (bf16)v;
        else
          Vt[(((size_t)bh * 64 + (n >> 6)) * 64 + d) * 64 + (n & 63)] = (bf16)v;
      }
    }
  }
}

// ---------------------------------------------------------------------------
// flash_partial v19: grid (32 strip128, 16 bh, 2 half), 4 waves, 32 Q
// rows/wave, 32 KV-tiles of 64. Merged phase clusters: QK(16 MFMA) ->
// SM(both halves) -> PV+l(20 MFMA). In-reg P (cvt_pk+permlane), exp2,
// ones-MFMA rowsum. K/V dbuf, one barrier/tile, reg-prefetch after barrier.
// ---------------------------------------------------------------------------
__global__ __launch_bounds__(256, 4) void flash_partial(const bf16* __restrict__ Q,
                                                        const bf16* __restrict__ K,
                                                        const bf16* __restrict__ Vt,
                                                        bf16* __restrict__ Opart,
                                                        float* __restrict__ Lpart) {
  int strip = blockIdx.x, bh = blockIdx.y, half = blockIdx.z;
  int tid = threadIdx.x;
  int wave = tid >> 6, lane = tid & 63;
  int l16 = lane & 15, quad = lane >> 4;

  const bf16* Qh = Q + (size_t)bh * 4096 * 64;
  const bf16* Kg = K + ((size_t)bh * 4096 + half * 2048) * 64;
  const bf16* Vg = Vt + (size_t)bh * 64 * 4096 + (size_t)half * 2048 * 64;

  __shared__ __align__(16) bf16 Klds[2][4096];
  __shared__ __align__(16) bf16 Vlds[2][4096];

  int qbase = strip * 128 + wave * 32;
  bf16x8 aq[2][2];
#pragma unroll
  for (int mt = 0; mt < 2; mt++) {
    const bf16* qr = Qh + (size_t)(qbase + mt * 16 + l16) * 64;
    aq[mt][0] = ldg8(qr + quad * 8);
    aq[mt][1] = ldg8(qr + 32 + quad * 8);
  }

  bf16x8 ones;
#pragma unroll
  for (int i = 0; i < 8; i++) ones[i] = (bf16)1.0f;

  f32x4 o[2][4] = {};
  f32x4 acc_l[2] = {};

  int e0 = tid * 8, e1 = (256 + tid) * 8;
  int r0 = e0 >> 6, r1 = e1 >> 6;
  int u0 = r0 * 8 + (((e0 & 63) >> 3) ^ (r0 & 7));
  int u1 = r1 * 8 + (((e1 & 63) >> 3) ^ (r1 & 7));

  bf16x8 kp0 = ldg8(Kg + e0), kp1 = ldg8(Kg + e1);
  bf16x8 vp0 = ldg8(Vg + e0), vp1 = ldg8(Vg + e1);

#pragma unroll 2
  for (int t = 0; t < 32; t++) {
    int cur = t & 1;
    bf16* kl = Klds[cur];
    bf16* vl = Vlds[cur];
    *(bf16x8*)&kl[u0 * 8] = kp0;
    *(bf16x8*)&kl[u1 * 8] = kp1;
    *(bf16x8*)&vl[u0 * 8] = vp0;
    *(bf16x8*)&vl[u1 * 8] = vp1;
    __syncthreads();

    if (t < 31) {
      const bf16* kg = Kg + (size_t)(t + 1) * 4096;
      const bf16* vg = Vg + (size_t)(t + 1) * 4096;
      kp0 = ldg8(kg + e0);
      kp1 = ldg8(kg + e1);
      vp0 = ldg8(vg + e0);
      vp1 = ldg8(vg + e1);
    }

    // ---- S^T = K Q^T for BOTH 32-kv halves (one 16-MFMA cluster) ----
    f32x4 s[2][2][2] = {};  // [h2][mt][c2]
    __builtin_amdgcn_s_setprio(1);
#pragma unroll
    for (int h2 = 0; h2 < 2; h2++)
#pragma unroll
      for (int c2 = 0; c2 < 2; c2++) {
        int n = h2 * 32 + c2 * 16 + l16;
        bf16x8 k0 = *(const bf16x8*)&kl[(n * 8 + (quad ^ (n & 7))) * 8];
        bf16x8 k1 = *(const bf16x8*)&kl[(n * 8 + ((4 + quad) ^ (n & 7))) * 8];
#pragma unroll
        for (int mt = 0; mt < 2; mt++) {
          s[h2][mt][c2] = MFMA16(k0, aq[mt][0], s[h2][mt][c2]);
          s[h2][mt][c2] = MFMA16(k1, aq[mt][1], s[h2][mt][c2]);
        }
      }
    __builtin_amdgcn_s_setprio(0);

    // ---- softmax both halves: p = exp2(s), pack + quad-redistribute ----
    bf16x8 pa[2][2];  // [h2][mt]
#pragma unroll
    for (int h2 = 0; h2 < 2; h2++)
#pragma unroll
      for (int mt = 0; mt < 2; mt++) {
        unsigned ue[2], wo[2];
#pragma unroll
        for (int c2 = 0; c2 < 2; c2++) {
          float p0 = __builtin_amdgcn_exp2f(s[h2][mt][c2][0]);
          float p1 = __builtin_amdgcn_exp2f(s[h2][mt][c2][1]);
          float p2 = __builtin_amdgcn_exp2f(s[h2][mt][c2][2]);
          float p3 = __builtin_amdgcn_exp2f(s[h2][mt][c2][3]);
          ue[c2] = cvt_pk_bf16(p0, p1);
          wo[c2] = cvt_pk_bf16(p2, p3);
        }
        pl32_swap(ue[0], ue[1]);
        pl16_swap(ue[0], ue[1]);
        pl32_swap(wo[0], wo[1]);
        pl16_swap(wo[0], wo[1]);
        u32x4 pk = {ue[0], wo[0], ue[1], wo[1]};
        pa[h2][mt] = __builtin_bit_cast(bf16x8, pk);
      }

    // ---- O += P V (both halves); l += P ones (one 20-MFMA cluster) ----
    __builtin_amdgcn_s_setprio(1);
    acc_l[0] = MFMA16(pa[0][0], ones, acc_l[0]);
    acc_l[1] = MFMA16(pa[0][1], ones, acc_l[1]);
    acc_l[0] = MFMA16(pa[1][0], ones, acc_l[0]);
    acc_l[1] = MFMA16(pa[1][1], ones, acc_l[1]);
#pragma unroll
    for (int h2 = 0; h2 < 2; h2++)
#pragma unroll
      for (int ct = 0; ct < 4; ct++) {
        int d = ct * 16 + l16;
        bf16x8 bv = *(const bf16x8*)&vl[(d * 8 + ((h2 * 4 + quad) ^ (d & 7))) * 8];
        o[0][ct] = MFMA16(pa[h2][0], bv, o[0][ct]);
        o[1][ct] = MFMA16(pa[h2][1], bv, o[1][ct]);
      }
    __builtin_amdgcn_s_setprio(0);
  }

  // ---- epilogue: partial o (bf16) + l (fp32, shuffle-free) ----
  size_t ub = ((size_t)half * 16 + bh) * 32 + strip;
  bf16* op = Opart + ub * 8192;
#pragma unroll
  for (int mt = 0; mt < 2; mt++) {
#pragma unroll
    for (int ct = 0; ct < 4; ct++)
#pragma unroll
      for (int r = 0; r < 4; r++)
        op[(wave * 32 + mt * 16 + quad * 4 + r) * 64 + ct * 16 + l16] =
            (bf16)o[mt][ct][r];
    if (l16 == 0) {
#pragma unroll
      for (int r = 0; r < 4; r++)
        Lpart[ub * 128 + wave * 32 + mt * 16 + quad * 4 + r] = acc_l[mt][r];
    }
  }
}

// ---------------------------------------------------------------------------
// flash_combine: Ap(P32-packed for out_gemm) = (o0+o1)/(l0+l1).
// Grid (64 mt, 16 kc); block per output tile(mt,kc) of 128x32.
// ---------------------------------------------------------------------------
__global__ __launch_bounds__(256) void flash_combine(const bf16* __restrict__ Opart,
                                                     const float* __restrict__ Lpart,
                                                     bf16* __restrict__ Ap) {
  int mt = blockIdx.x, kc = blockIdx.y;
  int b = mt >> 5, strip = mt & 31;
  int h = kc >> 1, d0 = (kc & 1) * 32;
  int bh = b * 8 + h;
  size_t u0 = (size_t)bh * 32 + strip;
  size_t u1 = ((size_t)16 + bh) * 32 + strip;
  bf16* dst = Ap + ((size_t)mt * 16 + kc) * 4096;
#pragma unroll
  for (int hf = 0; hf < 2; hf++) {
    int U = threadIdx.x + hf * 256;  // unit = kchunk*128 + r
    int kchunk = U >> 7, r = U & 127;
    bf16x8 o0 = ldg8(&Opart[u0 * 8192 + r * 64 + d0 + kchunk * 8]);
    bf16x8 o1 = ldg8(&Opart[u1 * 8192 + r * 64 + d0 + kchunk * 8]);
    float ls = Lpart[u0 * 128 + r] + Lpart[u1 * 128 + r];
    float rl = 1.0f / ls;
    bf16x8 ov;
#pragma unroll
    for (int j = 0; j < 8; j++) ov[j] = (bf16)(((float)o0[j] + (float)o1[j]) * rl);
    *(bf16x8*)&dst[U * 8] = ov;
  }
}

// ---------------------------------------------------------------------------
// Output projection, 128x128 tiles: Ap(P32) @ Wp2(P32T) + bias -> FP32.
// Grid (64 mt, 4 nt).
// ---------------------------------------------------------------------------
__global__ __launch_bounds__(256, 3) void out_gemm(const bf16* __restrict__ Ap,
                                                   const bf16* __restrict__ Wp2,
                                                   const float* __restrict__ bout,
                                                   float* __restrict__ Out) {
  int mt = blockIdx.x, nt = blockIdx.y;
  int tid = threadIdx.x;
  int wave = tid >> 6, lane = tid & 63;
  int l16 = lane & 15, quad = lane >> 4;
  int wr = wave >> 1, wc = wave & 1;

  __shared__ __align__(16) bf16 Ab[2][4096];
  __shared__ __align__(16) bf16 Bb[2][4096];

  f32x4 acc[4][4] = {};
  gemm128_core(Ap + (size_t)mt * 16 * 4096, Wp2 + (size_t)nt * 16 * 4096,
               Ab[0], Ab[1], Bb[0], Bb[1], tid, wr, wc, l16, quad, acc);

#pragma unroll
  for (int fj = 0; fj < 4; fj++) {
    int c = nt * 128 + wc * 64 + fj * 16 + l16;
    float bias = bout[c];
#pragma unroll
    for (int fi = 0; fi < 4; fi++) {
#pragma unroll
      for (int r = 0; r < 4; r++) {
        int m = mt * 128 + wr * 64 + fi * 16 + quad * 4 + r;
        Out[(size_t)m * 512 + c] = acc[fi][fj][r] + bias;
      }
    }
  }
}

// ---------------------------------------------------------------------------
// ws layout (no overlays; end 61,341,696 — same end as proven r14 layout):
//   Q 0 (8.39M) | K 8388608 | Vt 16777216 | Wp2 25165824 (0.52M) |
//   Opart 25690112 (16.78M) | Lpart 42467328 (0.52M) | Xp 42991616 (8.39M) |
//   Wp1 51380224 (1.57M) | Ap 52953088 (8.39M)
// ---------------------------------------------------------------------------
extern "C" void kernel_launch(void* const* d_in, const int* in_sizes, int n_in,
                              void* d_out, int out_size, void* d_ws,
                              size_t ws_size, hipStream_t stream) {
  const float* x = (const float*)d_in[0];
  const float* w_qkv = (const float*)d_in[1];
  const float* b_qkv = (const float*)d_in[2];
  const float* w_out = (const float*)d_in[3];
  const float* b_out = (const float*)d_in[4];
  float* out = (float*)d_out;

  char* ws = (char*)d_ws;
  bf16* Q = (bf16*)(ws + 0);
  bf16* K = (bf16*)(ws + 8388608);
  bf16* Vt = (bf16*)(ws + 16777216);
  bf16* Wp2 = (bf16*)(ws + 25165824);
  bf16* Opart = (bf16*)(ws + 25690112);
  float* Lpart = (float*)(ws + 42467328);
  bf16* Xp = (bf16*)(ws + 42991616);
  bf16* Wp1 = (bf16*)(ws + 51380224);
  bf16* Ap = (bf16*)(ws + 52953088);

  cvt_pack_x<<<dim3(64, 16), 256, 0, stream>>>(x, Xp);
  transpose_pack_w<<<dim3(16, 12), 256, 0, stream>>>(w_qkv, Wp1, 1536);
  transpose_pack_w<<<dim3(16, 4), 256, 0, stream>>>(w_out, Wp2, 512);
  qkv_gemm<<<dim3(64, 12), 256, 0, stream>>>(Xp, Wp1, b_qkv, Q, K, Vt);
  flash_partial<<<dim3(32, 16, 2), 256, 0, stream>>>(Q, K, Vt, Opart, Lpart);
  flash_combine<<<dim3(64, 16), 256, 0, stream>>>(Opart, Lpart, Ap);
  out_gemm<<<dim3(64, 4), 256, 0, stream>>>(Ap, Wp2, b_out, out);
}